// Round 1
// baseline (439.917 us; speedup 1.0000x reference)
//
#include <hip/hip_runtime.h>

// reference(x, p, true_sum, true_carry) = jnp.sum(x[:,0]) * 0.0 + 1.0
// => constant scalar 1.0f (float32). No input data affects the output
// (sum of finite 0/1 floats * 0.0 == 0.0). Single-thread constant store.

__global__ void write_one_kernel(float* out) {
    out[0] = 1.0f;
}

extern "C" void kernel_launch(void* const* d_in, const int* in_sizes, int n_in,
                              void* d_out, int out_size, void* d_ws, size_t ws_size,
                              hipStream_t stream) {
    (void)d_in; (void)in_sizes; (void)n_in; (void)out_size; (void)d_ws; (void)ws_size;
    write_one_kernel<<<1, 1, 0, stream>>>((float*)d_out);
}